// Round 7
// baseline (91.217 us; speedup 1.0000x reference)
//
#include <hip/hip_runtime.h>
#include <math.h>

#define NH 512
#define NO 512
#define BT_TOT 256
#define HID 64
#define OUTD 128

// d_ws float layout
#define WS_DMIN 0                       // [bt][512] dmin_h
#define WS_S1   (BT_TOT * 512)          // [bt][half(2)][wave(4)][qty(4): w,dx,dy,dz]
#define WS_S2   (WS_S1 + BT_TOT * 32)   // [bt][half(2)][wave(4)] dmo partials

typedef float float2v __attribute__((ext_vector_type(2)));

__device__ __forceinline__ float wave_sum(float v) {
    #pragma unroll
    for (int off = 32; off > 0; off >>= 1) v += __shfl_xor(v, off, 64);
    return v;
}

// K1: grid 512 = 2 blocks per bt (2 blocks/CU). Block (bt, half):
//   t<256 : pass1 — humans [half*256, +256) vs all 512 objects. Q=8: thread
//           (s=t>>5, ql=t&31) handles queries {ql+32j} over objects [64s,64s+64).
//   t>=256: pass2 — objects [half*256, +256) vs all 512 humans, same shape.
// Tables T = (-2x,-2y,-2z,||p||^2) SoA in LDS. Arithmetic identical to prior round.
__global__ __launch_bounds__(512) void ie_dist(
    const float* __restrict__ h_in, const float* __restrict__ o_in,
    const float* __restrict__ sh_in, float* __restrict__ ws)
{
    __shared__ __align__(16) float Ox[NO], Oy[NO], Oz[NO], Ow[NO];
    __shared__ __align__(16) float Hx[NH], Hy[NH], Hz[NH], Hw[NH];
    __shared__ float p1v[8 * 256];
    __shared__ int   p1i[8 * 256];
    __shared__ float p2v[8 * 256];

    const int b = blockIdx.x, bt = b >> 1, half = b & 1;
    const int t = threadIdx.x, lane = t & 63, wv = t >> 6;
    const int base = half << 8;

    // ---- build both SoA tables (each thread: one object + one human) ----
    {
        const float* op = o_in + ((size_t)bt * NO + t) * 3;
        float x = op[0], y = op[1], z = op[2];
        Ox[t] = -2.f * x; Oy[t] = -2.f * y; Oz[t] = -2.f * z; Ow[t] = x * x + y * y + z * z;
        const float* hp = h_in + ((size_t)bt * NH + t) * 3;
        x = hp[0]; y = hp[1]; z = hp[2];
        Hx[t] = -2.f * x; Hy[t] = -2.f * y; Hz[t] = -2.f * z; Hw[t] = x * x + y * y + z * z;
    }
    __syncthreads();   // B1

    if (t < 256) {
        const int s = t >> 5, ql = t & 31, sbase = s << 6;
        float qx[8], qy[8], qz[8], bb[8];
        int   bi[8];
        #pragma unroll
        for (int j = 0; j < 8; j++) {
            const int hq = base + ql + 32 * j;
            qx[j] = -0.5f * Hx[hq]; qy[j] = -0.5f * Hy[hq]; qz[j] = -0.5f * Hz[hq];
            bb[j] = 1e30f; bi[j] = sbase;
        }
        #pragma unroll 2
        for (int n = 0; n < 64; n += 4) {
            float4 X = *(const float4*)&Ox[sbase + n];
            float4 Y = *(const float4*)&Oy[sbase + n];
            float4 Z = *(const float4*)&Oz[sbase + n];
            float4 W = *(const float4*)&Ow[sbase + n];
            float2v xlo = {X.x, X.y}, xhi = {X.z, X.w};
            float2v ylo = {Y.x, Y.y}, yhi = {Y.z, Y.w};
            float2v zlo = {Z.x, Z.y}, zhi = {Z.z, Z.w};
            float2v wlo = {W.x, W.y}, whi = {W.z, W.w};
            #pragma unroll
            for (int j = 0; j < 8; j++) {
                float2v qxs = {qx[j], qx[j]}, qys = {qy[j], qy[j]}, qzs = {qz[j], qz[j]};
                float2v dlo = __builtin_elementwise_fma(qzs, zlo,
                               __builtin_elementwise_fma(qys, ylo,
                                __builtin_elementwise_fma(qxs, xlo, wlo)));
                float2v dhi = __builtin_elementwise_fma(qzs, zhi,
                               __builtin_elementwise_fma(qys, yhi,
                                __builtin_elementwise_fma(qxs, xhi, whi)));
                // strict <, ascending index => first-index tie-break
                if (dlo.x < bb[j]) { bb[j] = dlo.x; bi[j] = sbase + n;     }
                if (dlo.y < bb[j]) { bb[j] = dlo.y; bi[j] = sbase + n + 1; }
                if (dhi.x < bb[j]) { bb[j] = dhi.x; bi[j] = sbase + n + 2; }
                if (dhi.y < bb[j]) { bb[j] = dhi.y; bi[j] = sbase + n + 3; }
            }
        }
        #pragma unroll
        for (int j = 0; j < 8; j++) {
            p1v[s * 256 + ql + 32 * j] = bb[j];
            p1i[s * 256 + ql + 32 * j] = bi[j];
        }
    } else {
        const int u = t - 256, s = u >> 5, ql = u & 31, sbase = s << 6;
        float qx[8], qy[8], qz[8], cc[8];
        #pragma unroll
        for (int j = 0; j < 8; j++) {
            const int oq = base + ql + 32 * j;
            qx[j] = -0.5f * Ox[oq]; qy[j] = -0.5f * Oy[oq]; qz[j] = -0.5f * Oz[oq];
            cc[j] = 1e30f;
        }
        #pragma unroll 2
        for (int n = 0; n < 64; n += 4) {
            float4 X = *(const float4*)&Hx[sbase + n];
            float4 Y = *(const float4*)&Hy[sbase + n];
            float4 Z = *(const float4*)&Hz[sbase + n];
            float4 W = *(const float4*)&Hw[sbase + n];
            float2v xlo = {X.x, X.y}, xhi = {X.z, X.w};
            float2v ylo = {Y.x, Y.y}, yhi = {Y.z, Y.w};
            float2v zlo = {Z.x, Z.y}, zhi = {Z.z, Z.w};
            float2v wlo = {W.x, W.y}, whi = {W.z, W.w};
            #pragma unroll
            for (int j = 0; j < 8; j++) {
                float2v qxs = {qx[j], qx[j]}, qys = {qy[j], qy[j]}, qzs = {qz[j], qz[j]};
                float2v dlo = __builtin_elementwise_fma(qzs, zlo,
                               __builtin_elementwise_fma(qys, ylo,
                                __builtin_elementwise_fma(qxs, xlo, wlo)));
                float2v dhi = __builtin_elementwise_fma(qzs, zhi,
                               __builtin_elementwise_fma(qys, yhi,
                                __builtin_elementwise_fma(qxs, xhi, whi)));
                cc[j] = fminf(cc[j], fminf(fminf(dlo.x, dlo.y), fminf(dhi.x, dhi.y)));
            }
        }
        #pragma unroll
        for (int j = 0; j < 8; j++) p2v[s * 256 + ql + 32 * j] = cc[j];
    }
    __syncthreads();   // B2

    // ---- combine substream partials, write compact results to ws ----
    if (t < 256) {
        const int gh = base + t;
        float best = p1v[t]; int bm = p1i[t];
        #pragma unroll
        for (int s = 1; s < 8; s++) {
            float pv = p1v[s * 256 + t];
            int   pi = p1i[s * 256 + t];
            if (pv < best) { best = pv; bm = pi; }  // ascending s => lowest index on tie
        }
        const float px = -0.5f * Hx[gh], py = -0.5f * Hy[gh], pz = -0.5f * Hz[gh];
        const float dmin = sqrtf(fmaxf(Hw[gh] + best, 0.f));
        const float ox = -0.5f * Ox[bm], oy = -0.5f * Oy[bm], oz = -0.5f * Oz[bm];
        const float vx = ox - px, vy = oy - py, vz = oz - pz;
        const float n2 = vx * vx + vy * vy + vz * vz;
        const float inv = 1.0f / sqrtf(fmaxf(n2, 1e-6f));
        const float w = expf(-dmin * 20.0f) * sh_in[(size_t)bt * NH + gh];
        ws[WS_DMIN + bt * 512 + gh] = dmin;
        float s0 = wave_sum(w), s1 = wave_sum(vx * inv), s2 = wave_sum(vy * inv), s3 = wave_sum(vz * inv);
        if (lane == 0) {
            float* dst = ws + WS_S1 + bt * 32 + half * 16 + wv * 4;
            dst[0] = s0; dst[1] = s1; dst[2] = s2; dst[3] = s3;
        }
    } else {
        const int t2 = t - 256, go = base + t2;
        float c = p2v[t2];
        #pragma unroll
        for (int s = 1; s < 8; s++) c = fminf(c, p2v[s * 256 + t2]);
        const float dmo = sqrtf(fmaxf(Ow[go] + c, 0.f));
        float s4 = wave_sum(dmo);
        if (lane == 0) ws[WS_S2 + bt * 8 + half * 4 + (wv - 4)] = s4;
    }
}

// K2: grid 256 × 512 threads — sort dmin_h, quantile prefix means, feats, MLP.
__global__ __launch_bounds__(512) void ie_post(
    const float* __restrict__ ws,
    const float* __restrict__ W1, const float* __restrict__ b1,
    const float* __restrict__ W2, const float* __restrict__ b2,
    float* __restrict__ out)
{
    __shared__ float sdm[2][NH];
    __shared__ float wred[4][8];
    __shared__ float feats[16];
    __shared__ float hidden[HID];

    const int bt = blockIdx.x, t = threadIdx.x, lane = t & 63, wave = t >> 6;

    float v = ws[WS_DMIN + bt * 512 + t];   // coalesced

    if (t < 4) {
        float s = 0.f;
        #pragma unroll
        for (int k = 0; k < 8; k++) s += ws[WS_S1 + bt * 32 + k * 4 + t];
        feats[5 + t] = s * (1.0f / 512.0f);          // w mean, dir.xyz mean
    } else if (t == 4) {
        float s = 0.f;
        #pragma unroll
        for (int k = 0; k < 8; k++) s += ws[WS_S2 + bt * 8 + k];
        feats[9] = s * (1.0f / 512.0f);              // dmin_o mean
    }

    // ---- bitonic sort (512 elems, 512 threads); shuffles j<64, 1-barrier LDS j>=64 ----
    int buf = 0;
    for (int k2 = 2; k2 <= 512; k2 <<= 1) {
        for (int j = k2 >> 1; j > 0; j >>= 1) {
            float pv;
            if (j >= 64) {
                sdm[buf][t] = v;
                __syncthreads();
                pv = sdm[buf][t ^ j];
                buf ^= 1;
            } else {
                pv = __shfl_xor(v, j, 64);
            }
            const bool keepmin = (((t & k2) == 0) == ((t & j) == 0));
            v = keepmin ? fminf(v, pv) : fmaxf(v, pv);
        }
    }

    // ---- prefix means over sorted values ----
    {
        float s0 = wave_sum(t < 102 ? v : 0.f);
        float s1 = wave_sum(t < 256 ? v : 0.f);
        float s2 = wave_sum(t < 410 ? v : 0.f);
        float s3 = wave_sum(v);
        if (lane == 0) { wred[0][wave] = s0; wred[1][wave] = s1; wred[2][wave] = s2; wred[3][wave] = s3; }
        if (t == 0) feats[1] = v;  // sorted min
    }
    __syncthreads();
    if (t < 4) {
        float s = 0.f;
        #pragma unroll
        for (int w = 0; w < 8; w++) s += wred[t][w];
        const int   slot[4]  = {2, 3, 4, 0};
        const float scale[4] = {1.f / 102.f, 1.f / 256.f, 1.f / 410.f, 1.f / 512.f};
        feats[slot[t]] = s * scale[t];
    }
    __syncthreads();

    // ---- fused MLP: 10 -> 64 (ReLU) -> 128 ----
    if (t < HID) {
        float acc = b1[t];
        #pragma unroll
        for (int i = 0; i < 10; i++) acc += feats[i] * W1[i * HID + t];
        hidden[t] = fmaxf(acc, 0.0f);
    }
    __syncthreads();
    if (t < OUTD) {
        float acc = b2[t];
        #pragma unroll
        for (int j = 0; j < HID; j++) acc += hidden[j] * W2[j * OUTD + t];
        out[(size_t)bt * OUTD + t] = acc;
    }
}

extern "C" void kernel_launch(void* const* d_in, const int* in_sizes, int n_in,
                              void* d_out, int out_size, void* d_ws, size_t ws_size,
                              hipStream_t stream) {
    (void)in_sizes; (void)n_in; (void)out_size; (void)ws_size;
    const float* h_in  = (const float*)d_in[0];
    const float* o_in  = (const float*)d_in[1];
    const float* sh_in = (const float*)d_in[2];
    // d_in[3] (s_o) is dead after the [:, :10] slice
    const float* W1 = (const float*)d_in[4];
    const float* b1 = (const float*)d_in[5];
    const float* W2 = (const float*)d_in[6];
    const float* b2 = (const float*)d_in[7];
    float* out = (float*)d_out;
    float* ws  = (float*)d_ws;   // ~565 KB used

    ie_dist<<<2 * BT_TOT, 512, 0, stream>>>(h_in, o_in, sh_in, ws);
    ie_post<<<BT_TOT, 512, 0, stream>>>(ws, W1, b1, W2, b2, out);
}

// Round 8
// 88.844 us; speedup vs baseline: 1.0267x; 1.0267x over previous
//
#include <hip/hip_runtime.h>
#include <math.h>

#define NH 512
#define NO 512
#define BT_TOT 256
#define HID 64
#define OUTD 128

__device__ __forceinline__ float wave_sum(float v) {
    #pragma unroll
    for (int off = 32; off > 0; off >>= 1) v += __shfl_xor(v, off, 64);
    return v;
}

// Single kernel, 1024 threads per bt (R4 structure = best measured).
//  waves 0..7  (t<512) : pass1 — thread (l=t&63, wv=t>>6) handles humans {l+64j}
//                         vs object substream [64*wv, 64*wv+64)
//  waves 8..15 (t>=512): pass2 — objects vs human substream, same shape
// Tables T[p]=(-2x,-2y,-2z,||p||^2) AoS float4 in LDS (one ds_read_b128/entry).
// New vs R4: MLP weights + sh_in prefetched into registers BEFORE the distance
// loop (global-load latency hidden under ~20us of VALU), parked in LDS after the
// loop; bitonic sort double-buffered (6 barriers instead of 12).
__global__ __launch_bounds__(1024) void ie_kernel(
    const float* __restrict__ h_in, const float* __restrict__ o_in,
    const float* __restrict__ sh_in,
    const float* __restrict__ W1, const float* __restrict__ b1,
    const float* __restrict__ W2, const float* __restrict__ b2,
    float* __restrict__ out)
{
    __shared__ float4 Th[NH];           // 8 KB
    __shared__ float4 To[NO];           // 8 KB
    __shared__ float  p1val[8 * NH];    // 16 KB
    __shared__ int    p1idx[8 * NH];    // 16 KB
    __shared__ float  p2val[8 * NO];    // 16 KB
    __shared__ float  sdm[2][NH];       // 4 KB (double-buffered sort exchange)
    __shared__ float  wred[5][8];
    __shared__ float  feats[16];
    __shared__ float  sW1[10 * HID];    // 2.5 KB
    __shared__ float  sb1[HID];
    __shared__ float  sW2[HID * OUTD];  // 32 KB
    __shared__ float  sb2[OUTD];
    __shared__ float  hidden[HID];

    const int bt = blockIdx.x, t = threadIdx.x;
    const int wave = t >> 6, lane = t & 63;

    // ---- build tables in LDS ----
    if (t < NO) {
        const float* op = o_in + ((size_t)bt * NO + t) * 3;
        float x = op[0], y = op[1], z = op[2];
        To[t] = make_float4(-2.f * x, -2.f * y, -2.f * z, x * x + y * y + z * z);
    } else {
        const int hp_i = t - NO;
        const float* hp = h_in + ((size_t)bt * NH + hp_i) * 3;
        float x = hp[0], y = hp[1], z = hp[2];
        Th[hp_i] = make_float4(-2.f * x, -2.f * y, -2.f * z, x * x + y * y + z * z);
    }

    // ---- issue weight / score prefetch loads (complete during distance loop) ----
    float4 w2a = ((const float4*)W2)[t * 2];
    float4 w2b = ((const float4*)W2)[t * 2 + 1];
    float4 w1r = {0.f, 0.f, 0.f, 0.f};
    float  b1r = 0.f, b2r = 0.f;
    if (t < 160) w1r = ((const float4*)W1)[t];
    else if (t < 224) b1r = b1[t - 160];
    else if (t < 352) b2r = b2[t - 224];
    float sh_val = (t < 512) ? sh_in[(size_t)bt * NH + t] : 0.f;

    __syncthreads();

    // ---- main distance loops (Q=8 per thread) ----
    if (t < 512) {
        const int l = t & 63, wv = t >> 6;
        const int obase = wv << 6;
        float qx[8], qy[8], qz[8], bb[8];
        int   bi[8];
        #pragma unroll
        for (int j = 0; j < 8; j++) {
            float4 H = Th[l + 64 * j];
            qx[j] = -0.5f * H.x; qy[j] = -0.5f * H.y; qz[j] = -0.5f * H.z;
            bb[j] = 1e30f; bi[j] = obase;
        }
        for (int n = 0; n < 64; n += 4) {
            float4 o0 = To[obase + n],     o1 = To[obase + n + 1];
            float4 o2 = To[obase + n + 2], o3 = To[obase + n + 3];
            #pragma unroll
            for (int j = 0; j < 8; j++) {
                float a0 = fmaf(qz[j], o0.z, fmaf(qy[j], o0.y, fmaf(qx[j], o0.x, o0.w)));
                float a1 = fmaf(qz[j], o1.z, fmaf(qy[j], o1.y, fmaf(qx[j], o1.x, o1.w)));
                float a2 = fmaf(qz[j], o2.z, fmaf(qy[j], o2.y, fmaf(qx[j], o2.x, o2.w)));
                float a3 = fmaf(qz[j], o3.z, fmaf(qy[j], o3.y, fmaf(qx[j], o3.x, o3.w)));
                // strict < and ascending n => first-index tie-break within substream
                if (a0 < bb[j]) { bb[j] = a0; bi[j] = obase + n;     }
                if (a1 < bb[j]) { bb[j] = a1; bi[j] = obase + n + 1; }
                if (a2 < bb[j]) { bb[j] = a2; bi[j] = obase + n + 2; }
                if (a3 < bb[j]) { bb[j] = a3; bi[j] = obase + n + 3; }
            }
        }
        #pragma unroll
        for (int j = 0; j < 8; j++) {
            p1val[wv * NH + l + 64 * j] = bb[j];
            p1idx[wv * NH + l + 64 * j] = bi[j];
        }
    } else {
        const int u = t - 512, l = u & 63, wv = u >> 6;
        const int nbase = wv << 6;
        float qx[8], qy[8], qz[8], cc[8];
        #pragma unroll
        for (int j = 0; j < 8; j++) {
            float4 O = To[l + 64 * j];
            qx[j] = -0.5f * O.x; qy[j] = -0.5f * O.y; qz[j] = -0.5f * O.z;
            cc[j] = 1e30f;
        }
        for (int n = 0; n < 64; n += 4) {
            float4 r0 = Th[nbase + n],     r1 = Th[nbase + n + 1];
            float4 r2 = Th[nbase + n + 2], r3 = Th[nbase + n + 3];
            #pragma unroll
            for (int j = 0; j < 8; j++) {
                float e0 = fmaf(qz[j], r0.z, fmaf(qy[j], r0.y, fmaf(qx[j], r0.x, r0.w)));
                float e1 = fmaf(qz[j], r1.z, fmaf(qy[j], r1.y, fmaf(qx[j], r1.x, r1.w)));
                float e2 = fmaf(qz[j], r2.z, fmaf(qy[j], r2.y, fmaf(qx[j], r2.x, r2.w)));
                float e3 = fmaf(qz[j], r3.z, fmaf(qy[j], r3.y, fmaf(qx[j], r3.x, r3.w)));
                cc[j] = fminf(cc[j], fminf(fminf(e0, e1), fminf(e2, e3)));
            }
        }
        #pragma unroll
        for (int j = 0; j < 8; j++) p2val[wv * NO + l + 64 * j] = cc[j];
    }

    // ---- park prefetched weights in LDS (vmem long since landed) ----
    ((float4*)sW2)[t * 2]     = w2a;
    ((float4*)sW2)[t * 2 + 1] = w2b;
    if (t < 160) ((float4*)sW1)[t] = w1r;
    else if (t < 224) sb1[t - 160] = b1r;
    else if (t < 352) sb2[t - 224] = b2r;
    __syncthreads();

    // ---- combine 8 substream partials per point, per-point features ----
    float v = 0.f;          // dmin_h for sort (t<512)
    float w_t = 0.f, dx = 0.f, dy = 0.f, dz = 0.f, dmo_t = 0.f;
    if (t < 512) {
        float best = p1val[t]; int bm = p1idx[t];
        #pragma unroll
        for (int w = 1; w < 8; w++) {
            float pv = p1val[w * NH + t];
            int   pi = p1idx[w * NH + t];
            if (pv < best) { best = pv; bm = pi; }  // strict <, ascending w => lowest index on tie
        }
        float4 H = Th[t];
        const float px = -0.5f * H.x, py = -0.5f * H.y, pz = -0.5f * H.z;
        const float dmin_t = sqrtf(fmaxf(H.w + best, 0.f));
        float4 O = To[bm];
        const float vx = fmaf(-0.5f, O.x, -px), vy = fmaf(-0.5f, O.y, -py), vz = fmaf(-0.5f, O.z, -pz);
        const float n2 = vx * vx + vy * vy + vz * vz;
        const float inv = 1.0f / sqrtf(fmaxf(n2, 1e-6f));
        w_t = expf(-dmin_t * 20.0f) * sh_val;
        dx = vx * inv; dy = vy * inv; dz = vz * inv;
        v = dmin_t;
    } else {
        const int o = t - 512;
        float c = p2val[o];
        #pragma unroll
        for (int w = 1; w < 8; w++) c = fminf(c, p2val[w * NO + o]);
        dmo_t = sqrtf(fmaxf(To[o].w + c, 0.f));
    }

    // ---- reductions set 1 ----
    if (t < 512) {
        float s0 = wave_sum(w_t), s1 = wave_sum(dx), s2 = wave_sum(dy), s3 = wave_sum(dz);
        if (lane == 0) { wred[0][wave] = s0; wred[1][wave] = s1; wred[2][wave] = s2; wred[3][wave] = s3; }
    } else {
        float s4 = wave_sum(dmo_t);
        if (lane == 0) wred[4][wave - 8] = s4;
    }
    __syncthreads();
    if (t < 5) {
        float s = 0.f;
        #pragma unroll
        for (int w = 0; w < 8; w++) s += wred[t][w];
        const int slot[5] = {5, 6, 7, 8, 9};
        feats[slot[t]] = s * (1.0f / 512.0f);
    }

    // ---- bitonic sort of dmin_h (t<512); shuffles j<64, double-buffered LDS j>=64 ----
    int buf = 0;
    for (int k2 = 2; k2 <= 512; k2 <<= 1) {
        for (int j = k2 >> 1; j > 0; j >>= 1) {
            float pv;
            if (j >= 64) {
                if (t < 512) sdm[buf][t] = v;
                __syncthreads();
                pv = (t < 512) ? sdm[buf][t ^ j] : 0.f;
                buf ^= 1;   // next LDS stage uses the other buffer
            } else {
                pv = __shfl_xor(v, j, 64);
            }
            if (t < 512) {
                const bool keepmin = (((t & k2) == 0) == ((t & j) == 0));
                v = keepmin ? fminf(v, pv) : fmaxf(v, pv);
            }
        }
    }

    // ---- reductions set 2: prefix means over sorted dmin_h ----
    if (t < 512) {
        float s0 = wave_sum(t < 102 ? v : 0.f);
        float s1 = wave_sum(t < 256 ? v : 0.f);
        float s2 = wave_sum(t < 410 ? v : 0.f);
        float s3 = wave_sum(v);
        if (lane == 0) { wred[0][wave] = s0; wred[1][wave] = s1; wred[2][wave] = s2; wred[3][wave] = s3; }
        if (t == 0) feats[1] = v;  // sorted min
    }
    __syncthreads();
    if (t < 4) {
        float s = 0.f;
        #pragma unroll
        for (int w = 0; w < 8; w++) s += wred[t][w];
        const int   slot[4]  = {2, 3, 4, 0};
        const float scale[4] = {1.f / 102.f, 1.f / 256.f, 1.f / 410.f, 1.f / 512.f};
        feats[slot[t]] = s * scale[t];
    }
    __syncthreads();

    // ---- fused MLP from LDS weights: 10 -> 64 (ReLU) -> 128 ----
    if (t < HID) {
        float acc = sb1[t];
        #pragma unroll
        for (int i = 0; i < 10; i++) acc += feats[i] * sW1[i * HID + t];
        hidden[t] = fmaxf(acc, 0.0f);
    }
    __syncthreads();
    if (t < OUTD) {
        float acc = sb2[t];
        #pragma unroll
        for (int j = 0; j < HID; j++) acc += hidden[j] * sW2[j * OUTD + t];
        out[(size_t)bt * OUTD + t] = acc;
    }
}

extern "C" void kernel_launch(void* const* d_in, const int* in_sizes, int n_in,
                              void* d_out, int out_size, void* d_ws, size_t ws_size,
                              hipStream_t stream) {
    (void)in_sizes; (void)n_in; (void)out_size; (void)d_ws; (void)ws_size;
    const float* h_in  = (const float*)d_in[0];
    const float* o_in  = (const float*)d_in[1];
    const float* sh_in = (const float*)d_in[2];
    // d_in[3] (s_o) is dead after the [:, :10] slice
    const float* W1 = (const float*)d_in[4];
    const float* b1 = (const float*)d_in[5];
    const float* W2 = (const float*)d_in[6];
    const float* b2 = (const float*)d_in[7];
    float* out = (float*)d_out;

    ie_kernel<<<BT_TOT, 1024, 0, stream>>>(h_in, o_in, sh_in, W1, b1, W2, b2, out);
}